// Round 2
// baseline (1321.040 us; speedup 1.0000x reference)
//
#include <hip/hip_runtime.h>
#include <hip/hip_bf16.h>

#define NN 100000
#define NE 3200000
#define NPB 64        // dst nodes per bucket
#define NB 1564       // 1564*64 = 100096 >= NN
#define CAP 2560      // mean 2046, sigma ~45 -> +11 sigma headroom
#define BATCH 8192    // edges staged per bin_k block

typedef __hip_bfloat16 bf16;

__device__ __forceinline__ void fma4(float4& a, float s, const float4 w) {
  a.x = fmaf(s, w.x, a.x);
  a.y = fmaf(s, w.y, a.y);
  a.z = fmaf(s, w.z, a.z);
  a.w = fmaf(s, w.w, a.w);
}

__device__ __forceinline__ unsigned short f2b(float f) {  // f32 -> bf16 RNE
  unsigned u = __float_as_uint(f);
  unsigned r = ((u >> 16) & 1u) + 0x7FFFu;
  return (unsigned short)((u + r) >> 16);
}

__device__ __forceinline__ unsigned pack2(float lo, float hi) {
  return (unsigned)f2b(lo) | ((unsigned)f2b(hi) << 16);
}

// Detect whether edge_index is int64 (high dwords of first 64 values all zero) or int32.
__global__ void detect_k(const int* __restrict__ e, int* __restrict__ flag) {
  unsigned long long b = __ballot(e[2 * (int)threadIdx.x + 1] == 0);
  if (threadIdx.x == 0) flag[0] = (b == 0xFFFFFFFFFFFFFFFFULL) ? 1 : 0;
}

// Binning: LDS histogram -> bulk range reservation (1 global atomic per
// block*bucket) -> direct scatter via LDS cursors.
__global__ __launch_bounds__(1024) void bin_k(const void* __restrict__ eidx,
                                              const int* __restrict__ flag,
                                              int* __restrict__ bcur,
                                              int* __restrict__ buckets) {
  __shared__ int scnt[NB];
  __shared__ int lcur[NB];
  int t = threadIdx.x;
  long long e0 = (long long)blockIdx.x * BATCH;
  int m = (int)((NE - e0 < BATCH) ? (NE - e0) : BATCH);
  int isI64 = flag[0];

  for (int i = t; i < NB; i += 1024) scnt[i] = 0;
  __syncthreads();

  int ent[BATCH / 1024], bv[BATCH / 1024];
#pragma unroll
  for (int j = 0; j < BATCH / 1024; j++) {
    int idx = t + j * 1024;
    bv[j] = -1;
    if (idx < m) {
      long long i = e0 + idx;
      int s, d;
      if (isI64) {
        s = (int)((const long long*)eidx)[i];
        d = (int)((const long long*)eidx)[NE + i];
      } else {
        s = ((const int*)eidx)[i];
        d = ((const int*)eidx)[NE + i];
      }
      bv[j] = d >> 6;
      ent[j] = s | ((d & 63) << 17);
      atomicAdd(&scnt[bv[j]], 1);
    }
  }
  __syncthreads();
  for (int i = t; i < NB; i += 1024) {
    int c = scnt[i];
    lcur[i] = c ? atomicAdd(&bcur[i], c) : 0;
  }
  __syncthreads();
#pragma unroll
  for (int j = 0; j < BATCH / 1024; j++) {
    if (bv[j] >= 0) {
      int pos = atomicAdd(&lcur[bv[j]], 1);
      if (pos < CAP) buckets[(size_t)bv[j] * CAP + pos] = ent[j];
    }
  }
}

// Per-bucket LDS histogram -> dinv + exact neighbor counts.
__global__ __launch_bounds__(256) void cnt_k(const int* __restrict__ buckets,
                                             const int* __restrict__ bcur,
                                             float* __restrict__ dinv,
                                             int* __restrict__ counts) {
  __shared__ int cnt[NPB];
  int b = blockIdx.x, t = threadIdx.x;
  if (t < NPB) cnt[t] = 0;
  __syncthreads();
  int m = bcur[b]; if (m > CAP) m = CAP;
  const int* bp = buckets + (size_t)b * CAP;
  for (int i = t; i < m; i += 256) atomicAdd(&cnt[(bp[i] >> 17) & 63], 1);
  __syncthreads();
  int node = b * NPB + t;
  if (t < NPB && node < NN) {
    dinv[node] = rsqrtf((float)cnt[t] + 1.0f);
    counts[node] = cnt[t];
  }
}

// h' = (x @ W_gcn) * dinv[row], bf16 out.
// v3: row-per-lane, full W (256x64 = 64KB) resident in LDS (wave-uniform
// broadcast reads, conflict-free), x streamed per-lane in 64B lines with
// register double-buffering. All staging in NAMED float4 vars (no local
// arrays, no address-taken locals -> no scratch). Zero K-loop barriers.
__global__ __launch_bounds__(256) void gemm_k(const float* __restrict__ x,
                                              const float* __restrict__ W,
                                              const float* __restrict__ dinv,
                                              bf16* __restrict__ h) {
  __shared__ float sW[256 * 64];  // [k][c], 64 KB
  int t = threadIdx.x;
  {
    const float4* Wv = (const float4*)W;
    float4* sWv = (float4*)sW;
#pragma unroll
    for (int i = 0; i < 16; i++) sWv[t + i * 256] = Wv[t + i * 256];
  }
  __syncthreads();

  int r = blockIdx.x * 256 + t;
  int rc = r < NN ? r : NN - 1;                   // clamp loads, mask store
  const float4* xp = (const float4*)(x + (size_t)rc * 256);

  float4 acc[16];
#pragma unroll
  for (int i = 0; i < 16; i++) acc[i] = make_float4(0.f, 0.f, 0.f, 0.f);

  // one chunk = 16 floats = one 64B line per lane, in 4 named float4s
#define LOADC(P0, P1, P2, P3, c)   \
  {                                \
    P0 = xp[(c) * 4 + 0];          \
    P1 = xp[(c) * 4 + 1];          \
    P2 = xp[(c) * 4 + 2];          \
    P3 = xp[(c) * 4 + 3];          \
  }
#define FMA1(XV, k)                                           \
  {                                                           \
    float xv_ = (XV);                                         \
    const float4* wr_ = (const float4*)(sW + (k) * 64);       \
    _Pragma("unroll")                                         \
    for (int c = 0; c < 16; c++) fma4(acc[c], xv_, wr_[c]);   \
  }
#define FMA4(V, k0) FMA1(V.x, (k0)) FMA1(V.y, (k0) + 1) FMA1(V.z, (k0) + 2) FMA1(V.w, (k0) + 3)
#define CHUNK(P0, P1, P2, P3, k0) \
  FMA4(P0, (k0)) FMA4(P1, (k0) + 4) FMA4(P2, (k0) + 8) FMA4(P3, (k0) + 12)

  float4 a0, a1, a2, a3, b0, b1, b2, b3;
  LOADC(a0, a1, a2, a3, 0);
  for (int kc2 = 0; kc2 < 8; kc2++) {
    LOADC(b0, b1, b2, b3, 2 * kc2 + 1);            // prefetch odd chunk
    CHUNK(a0, a1, a2, a3, kc2 * 32);               // compute even chunk
    if (kc2 < 7) LOADC(a0, a1, a2, a3, 2 * kc2 + 2);  // prefetch next even
    CHUNK(b0, b1, b2, b3, kc2 * 32 + 16);          // compute odd chunk
  }
#undef LOADC
#undef FMA1
#undef FMA4
#undef CHUNK

  if (r < NN) {
    float dn = dinv[r];
    uint4* hp = (uint4*)(h + (size_t)r * 64);
#pragma unroll
    for (int i = 0; i < 8; i++) {
      uint4 v;
      v.x = pack2(acc[2 * i].x * dn,     acc[2 * i].y * dn);
      v.y = pack2(acc[2 * i].z * dn,     acc[2 * i].w * dn);
      v.z = pack2(acc[2 * i + 1].x * dn, acc[2 * i + 1].y * dn);
      v.w = pack2(acc[2 * i + 1].z * dn, acc[2 * i + 1].w * dn);
      hp[i] = v;
    }
  }
}

// Direct-accumulate aggregate v3: one block per 64-node bucket, 512 threads.
// Fixed-point (scale 2^15, bias 2^20 per 32-bit word) packed 2 feats per u64;
// native ds_add_u64 atomics (2 per edge). Entries staged in LDS; gather loop
// has no loop-carried deps -> deep pipelining.
__global__ __launch_bounds__(512) void agg_k(const bf16* __restrict__ h,
                                             const int* __restrict__ buckets,
                                             const int* __restrict__ bcur,
                                             const int* __restrict__ counts,
                                             const float* __restrict__ dinv,
                                             const float* __restrict__ bg,
                                             bf16* __restrict__ hg) {
  __shared__ unsigned long long acc[NPB * 33];  // 64 nodes x 32 pairs, stride 33
  __shared__ int ents[CAP];
  int b = blockIdx.x, t = threadIdx.x;
  int node0 = b * NPB;
  int m = bcur[b]; if (m > CAP) m = CAP;
  const int* bp = buckets + (size_t)b * CAP;
  for (int i = t; i < NPB * 33; i += 512) acc[i] = 0ULL;
  for (int i = t; i < m; i += 512) ents[i] = bp[i];
  __syncthreads();
  int w = t >> 6, lane = t & 63;
  int g = lane >> 4, fl = lane & 15;
  const unsigned short* hu = (const unsigned short*)h;
#pragma unroll 4
  for (int p = w * 4 + g; p < m; p += 32) {
    int e = ents[p];
    int src = e & 0x1FFFF;
    int dl = (e >> 17) & 63;
    uint2 v = *(const uint2*)(hu + (size_t)src * 64 + fl * 4);
    // bf16 -> f32 -> biased fixed point (all positive; round via +0.5 & trunc)
    unsigned i0 = (unsigned)fmaf(__uint_as_float(v.x << 16),          32768.f, 1048576.5f);
    unsigned i1 = (unsigned)fmaf(__uint_as_float(v.x & 0xFFFF0000u),  32768.f, 1048576.5f);
    unsigned i2 = (unsigned)fmaf(__uint_as_float(v.y << 16),          32768.f, 1048576.5f);
    unsigned i3 = (unsigned)fmaf(__uint_as_float(v.y & 0xFFFF0000u),  32768.f, 1048576.5f);
    unsigned long long u0 = (unsigned long long)i0 | ((unsigned long long)i1 << 32);
    unsigned long long u1 = (unsigned long long)i2 | ((unsigned long long)i3 << 32);
    unsigned long long* ap = acc + dl * 33 + fl * 2;
    atomicAdd(ap, u0);      // ds_add_u64, no return
    atomicAdd(ap + 1, u1);
  }
  __syncthreads();
  // epilogue: thread t -> node t>>3, feats (t&7)*8 .. +7
  int n = t >> 3, f0 = (t & 7) * 8;
  int node = node0 + n;
  if (node < NN) {
    int cnt = counts[node];
    unsigned bias32 = (unsigned)cnt << 20;
    float dn = dinv[node];
    const unsigned long long* ap = acc + n * 33 + (f0 >> 1);
    uint4 sv = *(const uint4*)(hu + (size_t)node * 64 + f0);   // self row, 8 bf16
    unsigned uu[4] = {sv.x, sv.y, sv.z, sv.w};
    const float* bb = bg + f0;
    unsigned short o[8];
#pragma unroll
    for (int j = 0; j < 4; j++) {
      unsigned long long u = ap[j];
      float vlo = (float)(int)((unsigned)u - bias32) * (1.f / 32768.f);
      float vhi = (float)(int)((unsigned)(u >> 32) - bias32) * (1.f / 32768.f);
      float slo = __uint_as_float(uu[j] << 16);
      float shi = __uint_as_float(uu[j] & 0xFFFF0000u);
      o[2 * j]     = f2b(fmaxf(fmaf(vlo + slo, dn, bb[2 * j]), 0.f));
      o[2 * j + 1] = f2b(fmaxf(fmaf(vhi + shi, dn, bb[2 * j + 1]), 0.f));
    }
    *(uint4*)((unsigned short*)hg + (size_t)node * 64 + f0) = *(uint4*)o;
  }
}

// Per-thread node MLP: 64 -> 32 -> 16 -> 4 + log_softmax.
__global__ __launch_bounds__(256) void mlp_k(const bf16* __restrict__ hg,
                                             const float* __restrict__ W1, const float* __restrict__ b1,
                                             const float* __restrict__ W2, const float* __restrict__ b2,
                                             const float* __restrict__ W3, const float* __restrict__ b3,
                                             float* __restrict__ out) {
  __shared__ float4 sW1[512];
  __shared__ float4 sW2[128];
  __shared__ float4 sW3[16];
  __shared__ float sb1[32], sb2[16], sb3[4];
  int t = threadIdx.x;
  for (int i = t; i < 512; i += 256) sW1[i] = ((const float4*)W1)[i];
  if (t < 128) sW2[t] = ((const float4*)W2)[t];
  if (t < 16)  sW3[t] = ((const float4*)W3)[t];
  if (t < 32)  sb1[t] = b1[t];
  if (t < 16)  sb2[t] = b2[t];
  if (t < 4)   sb3[t] = b3[t];
  __syncthreads();
  int n = blockIdx.x * 256 + t;
  if (n >= NN) return;
  float xr[64];
  const uint4* hp = (const uint4*)(hg + (size_t)n * 64);
#pragma unroll
  for (int i = 0; i < 8; i++) {
    uint4 v = hp[i];
    unsigned uu[4] = {v.x, v.y, v.z, v.w};
#pragma unroll
    for (int j = 0; j < 4; j++) {
      xr[8 * i + 2 * j]     = __uint_as_float(uu[j] << 16);
      xr[8 * i + 2 * j + 1] = __uint_as_float(uu[j] & 0xFFFF0000u);
    }
  }
  float4 a1[8];
#pragma unroll
  for (int j = 0; j < 8; j++) a1[j] = make_float4(sb1[4 * j], sb1[4 * j + 1], sb1[4 * j + 2], sb1[4 * j + 3]);
#pragma unroll
  for (int f = 0; f < 64; f++) {
    float xv = xr[f];
#pragma unroll
    for (int j = 0; j < 8; j++) fma4(a1[j], xv, sW1[f * 8 + j]);
  }
  float r2[32];
#pragma unroll
  for (int j = 0; j < 8; j++) {
    r2[4 * j + 0] = fmaxf(a1[j].x, 0.f);
    r2[4 * j + 1] = fmaxf(a1[j].y, 0.f);
    r2[4 * j + 2] = fmaxf(a1[j].z, 0.f);
    r2[4 * j + 3] = fmaxf(a1[j].w, 0.f);
  }
  float4 a2[4];
#pragma unroll
  for (int j = 0; j < 4; j++) a2[j] = make_float4(sb2[4 * j], sb2[4 * j + 1], sb2[4 * j + 2], sb2[4 * j + 3]);
#pragma unroll
  for (int f = 0; f < 32; f++) {
    float xv = r2[f];
#pragma unroll
    for (int j = 0; j < 4; j++) fma4(a2[j], xv, sW2[f * 4 + j]);
  }
  float r3[16];
#pragma unroll
  for (int j = 0; j < 4; j++) {
    r3[4 * j + 0] = fmaxf(a2[j].x, 0.f);
    r3[4 * j + 1] = fmaxf(a2[j].y, 0.f);
    r3[4 * j + 2] = fmaxf(a2[j].z, 0.f);
    r3[4 * j + 3] = fmaxf(a2[j].w, 0.f);
  }
  float4 a3 = make_float4(sb3[0], sb3[1], sb3[2], sb3[3]);
#pragma unroll
  for (int f = 0; f < 16; f++) fma4(a3, r3[f], sW3[f]);
  float m = fmaxf(fmaxf(a3.x, a3.y), fmaxf(a3.z, a3.w));
  float s = expf(a3.x - m) + expf(a3.y - m) + expf(a3.z - m) + expf(a3.w - m);
  float l = m + logf(s);
  ((float4*)out)[n] = make_float4(a3.x - l, a3.y - l, a3.z - l, a3.w - l);
}

extern "C" void kernel_launch(void* const* d_in, const int* in_sizes, int n_in,
                              void* d_out, int out_size, void* d_ws, size_t ws_size,
                              hipStream_t stream) {
  const float* x  = (const float*)d_in[0];
  const void* eidx = d_in[1];
  const float* Wg = (const float*)d_in[2];
  const float* bg = (const float*)d_in[3];
  const float* W1 = (const float*)d_in[4];
  const float* b1 = (const float*)d_in[5];
  const float* W2 = (const float*)d_in[6];
  const float* b2 = (const float*)d_in[7];
  const float* W3 = (const float*)d_in[8];
  const float* b3 = (const float*)d_in[9];

  char* ws = (char*)d_ws;
  bf16*  h       = (bf16*) (ws + 0);           // 12,800,000 B
  bf16*  hg      = (bf16*) (ws + 12800000);    // 12,800,000 B
  int*   buckets = (int*)  (ws + 25600000);    // 1564*2560*4 = 16,015,360 B
  float* dinv    = (float*)(ws + 41615360);    //    400,000 B
  int*   counts  = (int*)  (ws + 42015360);    //    400,000 B
  int*   bcur    = (int*)  (ws + 42415360);    //      6,256 B
  int*   flag    = (int*)  (ws + 42421632);

  detect_k<<<1, 64, 0, stream>>>((const int*)eidx, flag);
  hipMemsetAsync(bcur, 0, NB * sizeof(int), stream);
  bin_k<<<(NE + BATCH - 1) / BATCH, 1024, 0, stream>>>(eidx, flag, bcur, buckets);
  cnt_k<<<NB, 256, 0, stream>>>(buckets, bcur, dinv, counts);
  gemm_k<<<(NN + 255) / 256, 256, 0, stream>>>(x, Wg, dinv, h);
  agg_k<<<NB, 512, 0, stream>>>(h, buckets, bcur, counts, dinv, bg, hg);
  mlp_k<<<(NN + 255) / 256, 256, 0, stream>>>(hg, W1, b1, W2, b2, W3, b3, (float*)d_out);
}

// Round 4
// 205.276 us; speedup vs baseline: 6.4354x; 6.4354x over previous
//
#include <hip/hip_runtime.h>
#include <hip/hip_bf16.h>

#define NN 100000
#define NE 3200000
#define NPB 64        // dst nodes per bucket
#define NB 1564       // 1564*64 = 100096 >= NN
#define CAP 2560      // mean 2046, sigma ~45 -> +11 sigma headroom
#define BATCH 8192    // edges staged per bin_k block

typedef __hip_bfloat16 bf16;

__device__ __forceinline__ void fma4(float4& a, float s, const float4 w) {
  a.x = fmaf(s, w.x, a.x);
  a.y = fmaf(s, w.y, a.y);
  a.z = fmaf(s, w.z, a.z);
  a.w = fmaf(s, w.w, a.w);
}

__device__ __forceinline__ unsigned short f2b(float f) {  // f32 -> bf16 RNE
  unsigned u = __float_as_uint(f);
  unsigned r = ((u >> 16) & 1u) + 0x7FFFu;
  return (unsigned short)((u + r) >> 16);
}

__device__ __forceinline__ unsigned pack2(float lo, float hi) {
  return (unsigned)f2b(lo) | ((unsigned)f2b(hi) << 16);
}

// Detect whether edge_index is int64 (high dwords of first 64 values all zero) or int32.
__global__ void detect_k(const int* __restrict__ e, int* __restrict__ flag) {
  unsigned long long b = __ballot(e[2 * (int)threadIdx.x + 1] == 0);
  if (threadIdx.x == 0) flag[0] = (b == 0xFFFFFFFFFFFFFFFFULL) ? 1 : 0;
}

// Binning: LDS histogram -> bulk range reservation (1 global atomic per
// block*bucket) -> direct scatter via LDS cursors.
__global__ __launch_bounds__(1024) void bin_k(const void* __restrict__ eidx,
                                              const int* __restrict__ flag,
                                              int* __restrict__ bcur,
                                              int* __restrict__ buckets) {
  __shared__ int scnt[NB];
  __shared__ int lcur[NB];
  int t = threadIdx.x;
  long long e0 = (long long)blockIdx.x * BATCH;
  int m = (int)((NE - e0 < BATCH) ? (NE - e0) : BATCH);
  int isI64 = flag[0];

  for (int i = t; i < NB; i += 1024) scnt[i] = 0;
  __syncthreads();

  int ent[BATCH / 1024], bv[BATCH / 1024];
#pragma unroll
  for (int j = 0; j < BATCH / 1024; j++) {
    int idx = t + j * 1024;
    bv[j] = -1;
    if (idx < m) {
      long long i = e0 + idx;
      int s, d;
      if (isI64) {
        s = (int)((const long long*)eidx)[i];
        d = (int)((const long long*)eidx)[NE + i];
      } else {
        s = ((const int*)eidx)[i];
        d = ((const int*)eidx)[NE + i];
      }
      bv[j] = d >> 6;
      ent[j] = s | ((d & 63) << 17);
      atomicAdd(&scnt[bv[j]], 1);
    }
  }
  __syncthreads();
  for (int i = t; i < NB; i += 1024) {
    int c = scnt[i];
    lcur[i] = c ? atomicAdd(&bcur[i], c) : 0;
  }
  __syncthreads();
#pragma unroll
  for (int j = 0; j < BATCH / 1024; j++) {
    if (bv[j] >= 0) {
      int pos = atomicAdd(&lcur[bv[j]], 1);
      if (pos < CAP) buckets[(size_t)bv[j] * CAP + pos] = ent[j];
    }
  }
}

// Per-bucket LDS histogram -> dinv + exact neighbor counts.
__global__ __launch_bounds__(256) void cnt_k(const int* __restrict__ buckets,
                                             const int* __restrict__ bcur,
                                             float* __restrict__ dinv,
                                             int* __restrict__ counts) {
  __shared__ int cnt[NPB];
  int b = blockIdx.x, t = threadIdx.x;
  if (t < NPB) cnt[t] = 0;
  __syncthreads();
  int m = bcur[b]; if (m > CAP) m = CAP;
  const int* bp = buckets + (size_t)b * CAP;
  for (int i = t; i < m; i += 256) atomicAdd(&cnt[(bp[i] >> 17) & 63], 1);
  __syncthreads();
  int node = b * NPB + t;
  if (t < NPB && node < NN) {
    dinv[node] = rsqrtf((float)cnt[t] + 1.0f);
    counts[node] = cnt[t];
  }
}

// h' = (x @ W_gcn) * dinv[row], bf16 out.
// v7: thread owns 8 rows x 4 cols (acc = 32 VGPR). W (256x64 f32 = 64KB)
// LDS-resident, one barrier total; per k-quad only 4 ds_read_b128 amortized
// over 8 rows -> LDS:FMA = 1:32 (LDS pipe off the critical path). x streamed
// per-lane straight from global (L3-resident; duplicate addresses across the
// 16 threads sharing a row are HW-coalesced). Register double-buffered x,
// unroll-1 outer loop + sched_barrier to cap live set (VGPR target ~140).
__global__ __launch_bounds__(256, 3) void gemm_k(const float* __restrict__ x,
                                                 const float* __restrict__ W,
                                                 const float* __restrict__ dinv,
                                                 bf16* __restrict__ h) {
  __shared__ float sW[256 * 64];  // [k][c], 64 KB
  int t = threadIdx.x;
  {
    const float4* Wv = (const float4*)W;
    float4* sWv = (float4*)sW;
#pragma unroll
    for (int i = 0; i < 16; i++) sWv[t + i * 256] = Wv[t + i * 256];
  }
  __syncthreads();

  int fg = t & 15;        // col group: cols fg*4 .. fg*4+3
  int rq = t >> 4;        // row octet [0,16)
  int row0 = blockIdx.x * 128 + rq * 8;  // rows row0 .. row0+7

  // per-row clamped base pointers (clamp loads, mask stores)
#define XPTR(i) (const float4*)(x + (size_t)((row0 + (i)) < NN ? (row0 + (i)) : (NN - 1)) * 256)
  const float4* xp0 = XPTR(0); const float4* xp1 = XPTR(1);
  const float4* xp2 = XPTR(2); const float4* xp3 = XPTR(3);
  const float4* xp4 = XPTR(4); const float4* xp5 = XPTR(5);
  const float4* xp6 = XPTR(6); const float4* xp7 = XPTR(7);
#undef XPTR

  float4 acc0 = make_float4(0.f, 0.f, 0.f, 0.f), acc1 = acc0, acc2 = acc0,
         acc3 = acc0, acc4 = acc0, acc5 = acc0, acc6 = acc0, acc7 = acc0;

  const float4* sWv = (const float4*)sW;

#define LOADX(N, c)                                                        \
  {                                                                        \
    N##_0 = xp0[(c)]; N##_1 = xp1[(c)]; N##_2 = xp2[(c)]; N##_3 = xp3[(c)]; \
    N##_4 = xp4[(c)]; N##_5 = xp5[(c)]; N##_6 = xp6[(c)]; N##_7 = xp7[(c)]; \
  }
#define WCOMP(N, k4)                                                 \
  {                                                                  \
    float4 w0 = sWv[(4 * (k4) + 0) * 16 + fg];                       \
    float4 w1 = sWv[(4 * (k4) + 1) * 16 + fg];                       \
    float4 w2 = sWv[(4 * (k4) + 2) * 16 + fg];                       \
    float4 w3 = sWv[(4 * (k4) + 3) * 16 + fg];                       \
    fma4(acc0, N##_0.x, w0); fma4(acc0, N##_0.y, w1); fma4(acc0, N##_0.z, w2); fma4(acc0, N##_0.w, w3); \
    fma4(acc1, N##_1.x, w0); fma4(acc1, N##_1.y, w1); fma4(acc1, N##_1.z, w2); fma4(acc1, N##_1.w, w3); \
    fma4(acc2, N##_2.x, w0); fma4(acc2, N##_2.y, w1); fma4(acc2, N##_2.z, w2); fma4(acc2, N##_2.w, w3); \
    fma4(acc3, N##_3.x, w0); fma4(acc3, N##_3.y, w1); fma4(acc3, N##_3.z, w2); fma4(acc3, N##_3.w, w3); \
    fma4(acc4, N##_4.x, w0); fma4(acc4, N##_4.y, w1); fma4(acc4, N##_4.z, w2); fma4(acc4, N##_4.w, w3); \
    fma4(acc5, N##_5.x, w0); fma4(acc5, N##_5.y, w1); fma4(acc5, N##_5.z, w2); fma4(acc5, N##_5.w, w3); \
    fma4(acc6, N##_6.x, w0); fma4(acc6, N##_6.y, w1); fma4(acc6, N##_6.z, w2); fma4(acc6, N##_6.w, w3); \
    fma4(acc7, N##_7.x, w0); fma4(acc7, N##_7.y, w1); fma4(acc7, N##_7.z, w2); fma4(acc7, N##_7.w, w3); \
  }

  float4 xa_0, xa_1, xa_2, xa_3, xa_4, xa_5, xa_6, xa_7;
  float4 xb_0, xb_1, xb_2, xb_3, xb_4, xb_5, xb_6, xb_7;

  LOADX(xa, 0);
#pragma unroll 1
  for (int ku = 0; ku < 31; ku++) {
    LOADX(xb, 2 * ku + 1);
    WCOMP(xa, 2 * ku);
    LOADX(xa, 2 * ku + 2);
    WCOMP(xb, 2 * ku + 1);
    __builtin_amdgcn_sched_barrier(0);
  }
  LOADX(xb, 63);
  WCOMP(xa, 62);
  WCOMP(xb, 63);
#undef LOADX
#undef WCOMP

  // epilogue: row i -> h[row][fg*4 .. fg*4+3] (8 B store per row)
#define STORE(I, A)                                                  \
  {                                                                  \
    int row = row0 + (I);                                            \
    if (row < NN) {                                                  \
      float dn = dinv[row];                                          \
      uint2 v;                                                       \
      v.x = pack2(A.x * dn, A.y * dn);                               \
      v.y = pack2(A.z * dn, A.w * dn);                               \
      *(uint2*)((unsigned short*)h + (size_t)row * 64 + fg * 4) = v; \
    }                                                                \
  }
  STORE(0, acc0); STORE(1, acc1); STORE(2, acc2); STORE(3, acc3);
  STORE(4, acc4); STORE(5, acc5); STORE(6, acc6); STORE(7, acc7);
#undef STORE
}

// Direct-accumulate aggregate v3: one block per 64-node bucket, 512 threads.
// Fixed-point (scale 2^15, bias 2^20 per 32-bit word) packed 2 feats per u64;
// native ds_add_u64 atomics (2 per edge). Entries staged in LDS; gather loop
// has no loop-carried deps -> deep pipelining.
__global__ __launch_bounds__(512) void agg_k(const bf16* __restrict__ h,
                                             const int* __restrict__ buckets,
                                             const int* __restrict__ bcur,
                                             const int* __restrict__ counts,
                                             const float* __restrict__ dinv,
                                             const float* __restrict__ bg,
                                             bf16* __restrict__ hg) {
  __shared__ unsigned long long acc[NPB * 33];  // 64 nodes x 32 pairs, stride 33
  __shared__ int ents[CAP];
  int b = blockIdx.x, t = threadIdx.x;
  int node0 = b * NPB;
  int m = bcur[b]; if (m > CAP) m = CAP;
  const int* bp = buckets + (size_t)b * CAP;
  for (int i = t; i < NPB * 33; i += 512) acc[i] = 0ULL;
  for (int i = t; i < m; i += 512) ents[i] = bp[i];
  __syncthreads();
  int w = t >> 6, lane = t & 63;
  int g = lane >> 4, fl = lane & 15;
  const unsigned short* hu = (const unsigned short*)h;
#pragma unroll 4
  for (int p = w * 4 + g; p < m; p += 32) {
    int e = ents[p];
    int src = e & 0x1FFFF;
    int dl = (e >> 17) & 63;
    uint2 v = *(const uint2*)(hu + (size_t)src * 64 + fl * 4);
    // bf16 -> f32 -> biased fixed point (all positive; round via +0.5 & trunc)
    unsigned i0 = (unsigned)fmaf(__uint_as_float(v.x << 16),          32768.f, 1048576.5f);
    unsigned i1 = (unsigned)fmaf(__uint_as_float(v.x & 0xFFFF0000u),  32768.f, 1048576.5f);
    unsigned i2 = (unsigned)fmaf(__uint_as_float(v.y << 16),          32768.f, 1048576.5f);
    unsigned i3 = (unsigned)fmaf(__uint_as_float(v.y & 0xFFFF0000u),  32768.f, 1048576.5f);
    unsigned long long u0 = (unsigned long long)i0 | ((unsigned long long)i1 << 32);
    unsigned long long u1 = (unsigned long long)i2 | ((unsigned long long)i3 << 32);
    unsigned long long* ap = acc + dl * 33 + fl * 2;
    atomicAdd(ap, u0);      // ds_add_u64, no return
    atomicAdd(ap + 1, u1);
  }
  __syncthreads();
  // epilogue: thread t -> node t>>3, feats (t&7)*8 .. +7
  int n = t >> 3, f0 = (t & 7) * 8;
  int node = node0 + n;
  if (node < NN) {
    int cnt = counts[node];
    unsigned bias32 = (unsigned)cnt << 20;
    float dn = dinv[node];
    const unsigned long long* ap = acc + n * 33 + (f0 >> 1);
    uint4 sv = *(const uint4*)(hu + (size_t)node * 64 + f0);   // self row, 8 bf16
    unsigned uu[4] = {sv.x, sv.y, sv.z, sv.w};
    const float* bb = bg + f0;
    unsigned short o[8];
#pragma unroll
    for (int j = 0; j < 4; j++) {
      unsigned long long u = ap[j];
      float vlo = (float)(int)((unsigned)u - bias32) * (1.f / 32768.f);
      float vhi = (float)(int)((unsigned)(u >> 32) - bias32) * (1.f / 32768.f);
      float slo = __uint_as_float(uu[j] << 16);
      float shi = __uint_as_float(uu[j] & 0xFFFF0000u);
      o[2 * j]     = f2b(fmaxf(fmaf(vlo + slo, dn, bb[2 * j]), 0.f));
      o[2 * j + 1] = f2b(fmaxf(fmaf(vhi + shi, dn, bb[2 * j + 1]), 0.f));
    }
    *(uint4*)((unsigned short*)hg + (size_t)node * 64 + f0) = *(uint4*)o;
  }
}

// Per-thread node MLP: 64 -> 32 -> 16 -> 4 + log_softmax.
__global__ __launch_bounds__(256) void mlp_k(const bf16* __restrict__ hg,
                                             const float* __restrict__ W1, const float* __restrict__ b1,
                                             const float* __restrict__ W2, const float* __restrict__ b2,
                                             const float* __restrict__ W3, const float* __restrict__ b3,
                                             float* __restrict__ out) {
  __shared__ float4 sW1[512];
  __shared__ float4 sW2[128];
  __shared__ float4 sW3[16];
  __shared__ float sb1[32], sb2[16], sb3[4];
  int t = threadIdx.x;
  for (int i = t; i < 512; i += 256) sW1[i] = ((const float4*)W1)[i];
  if (t < 128) sW2[t] = ((const float4*)W2)[t];
  if (t < 16)  sW3[t] = ((const float4*)W3)[t];
  if (t < 32)  sb1[t] = b1[t];
  if (t < 16)  sb2[t] = b2[t];
  if (t < 4)   sb3[t] = b3[t];
  __syncthreads();
  int n = blockIdx.x * 256 + t;
  if (n >= NN) return;
  float xr[64];
  const uint4* hp = (const uint4*)(hg + (size_t)n * 64);
#pragma unroll
  for (int i = 0; i < 8; i++) {
    uint4 v = hp[i];
    unsigned uu[4] = {v.x, v.y, v.z, v.w};
#pragma unroll
    for (int j = 0; j < 4; j++) {
      xr[8 * i + 2 * j]     = __uint_as_float(uu[j] << 16);
      xr[8 * i + 2 * j + 1] = __uint_as_float(uu[j] & 0xFFFF0000u);
    }
  }
  float4 a1[8];
#pragma unroll
  for (int j = 0; j < 8; j++) a1[j] = make_float4(sb1[4 * j], sb1[4 * j + 1], sb1[4 * j + 2], sb1[4 * j + 3]);
#pragma unroll
  for (int f = 0; f < 64; f++) {
    float xv = xr[f];
#pragma unroll
    for (int j = 0; j < 8; j++) fma4(a1[j], xv, sW1[f * 8 + j]);
  }
  float r2[32];
#pragma unroll
  for (int j = 0; j < 8; j++) {
    r2[4 * j + 0] = fmaxf(a1[j].x, 0.f);
    r2[4 * j + 1] = fmaxf(a1[j].y, 0.f);
    r2[4 * j + 2] = fmaxf(a1[j].z, 0.f);
    r2[4 * j + 3] = fmaxf(a1[j].w, 0.f);
  }
  float4 a2[4];
#pragma unroll
  for (int j = 0; j < 4; j++) a2[j] = make_float4(sb2[4 * j], sb2[4 * j + 1], sb2[4 * j + 2], sb2[4 * j + 3]);
#pragma unroll
  for (int f = 0; f < 32; f++) {
    float xv = r2[f];
#pragma unroll
    for (int j = 0; j < 4; j++) fma4(a2[j], xv, sW2[f * 4 + j]);
  }
  float r3[16];
#pragma unroll
  for (int j = 0; j < 4; j++) {
    r3[4 * j + 0] = fmaxf(a2[j].x, 0.f);
    r3[4 * j + 1] = fmaxf(a2[j].y, 0.f);
    r3[4 * j + 2] = fmaxf(a2[j].z, 0.f);
    r3[4 * j + 3] = fmaxf(a2[j].w, 0.f);
  }
  float4 a3 = make_float4(sb3[0], sb3[1], sb3[2], sb3[3]);
#pragma unroll
  for (int f = 0; f < 16; f++) fma4(a3, r3[f], sW3[f]);
  float m = fmaxf(fmaxf(a3.x, a3.y), fmaxf(a3.z, a3.w));
  float s = expf(a3.x - m) + expf(a3.y - m) + expf(a3.z - m) + expf(a3.w - m);
  float l = m + logf(s);
  ((float4*)out)[n] = make_float4(a3.x - l, a3.y - l, a3.z - l, a3.w - l);
}

extern "C" void kernel_launch(void* const* d_in, const int* in_sizes, int n_in,
                              void* d_out, int out_size, void* d_ws, size_t ws_size,
                              hipStream_t stream) {
  const float* x  = (const float*)d_in[0];
  const void* eidx = d_in[1];
  const float* Wg = (const float*)d_in[2];
  const float* bg = (const float*)d_in[3];
  const float* W1 = (const float*)d_in[4];
  const float* b1 = (const float*)d_in[5];
  const float* W2 = (const float*)d_in[6];
  const float* b2 = (const float*)d_in[7];
  const float* W3 = (const float*)d_in[8];
  const float* b3 = (const float*)d_in[9];

  char* ws = (char*)d_ws;
  bf16*  h       = (bf16*) (ws + 0);           // 12,800,000 B
  bf16*  hg      = (bf16*) (ws + 12800000);    // 12,800,000 B
  int*   buckets = (int*)  (ws + 25600000);    // 1564*2560*4 = 16,015,360 B
  float* dinv    = (float*)(ws + 41615360);    //    400,000 B
  int*   counts  = (int*)  (ws + 42015360);    //    400,000 B
  int*   bcur    = (int*)  (ws + 42415360);    //      6,256 B
  int*   flag    = (int*)  (ws + 42421632);

  detect_k<<<1, 64, 0, stream>>>((const int*)eidx, flag);
  hipMemsetAsync(bcur, 0, NB * sizeof(int), stream);
  bin_k<<<(NE + BATCH - 1) / BATCH, 1024, 0, stream>>>(eidx, flag, bcur, buckets);
  cnt_k<<<NB, 256, 0, stream>>>(buckets, bcur, dinv, counts);
  gemm_k<<<(NN + 127) / 128, 256, 0, stream>>>(x, Wg, dinv, h);
  agg_k<<<NB, 512, 0, stream>>>(h, buckets, bcur, counts, dinv, bg, hg);
  mlp_k<<<(NN + 255) / 256, 256, 0, stream>>>(hg, W1, b1, W2, b2, W3, b3, (float*)d_out);
}